// Round 1
// baseline (976.567 us; speedup 1.0000x reference)
//
#include <hip/hip_runtime.h>
#include <hip/hip_bf16.h>
#include <math.h>

typedef __bf16 bf16;
typedef bf16  bf16x8 __attribute__((ext_vector_type(8)));
typedef float f32x4  __attribute__((ext_vector_type(4)));

#define CD 192
#define NHEADS 6

// One fragment convention for BOTH A and B operands of mfma_f32_16x16x32_bf16:
// lane l supplies (row/col) = r0 + (l&15), k = k0 + 8*(l>>4) + j  (8 contiguous bf16 = 16B).
// Any deviation of the HW k-map cancels because A and B use the identical map.
__device__ __forceinline__ bf16x8 ld_frag(const bf16* p, int r0, int k0, int ld) {
  const int l = threadIdx.x & 63;
  return *reinterpret_cast<const bf16x8*>(p + (r0 + (l & 15)) * ld + (k0 + 8 * (l >> 4)));
}

__device__ __forceinline__ f32x4 mfma16(bf16x8 a, bf16x8 b, f32x4 c) {
  return __builtin_amdgcn_mfma_f32_16x16x32_bf16(a, b, c, 0, 0, 0);
}

// ---------------- weight transpose + bf16 convert: dst[n*K+k] = src[k*N+n] ----------------
__global__ void prep_wt(const float* __restrict__ src, bf16* __restrict__ dst, int K, int N) {
  int i = blockIdx.x * 256 + threadIdx.x;
  if (i < K * N) {
    int k = i / N, n = i - k * N;
    dst[n * K + k] = (bf16)src[i];
  }
}

// ---------------- attention block: 1 block = 1 window (b, wh, ww); 6 waves = 6 heads -------
__global__ __launch_bounds__(384, 1)
void swin_attn_kernel(const float* __restrict__ x,
                      const float* __restrict__ n1w, const float* __restrict__ n1b,
                      const bf16* __restrict__ wtq, const float* __restrict__ qkvb,
                      const bf16* __restrict__ wtp, const float* __restrict__ projb,
                      const float* __restrict__ relb,
                      float* __restrict__ out)
{
  __shared__ alignas(16) bf16 sQ[NHEADS][64 * 40];   // [head][row 0..63][chan 0..31] pad 40
  __shared__ alignas(16) bf16 sK[NHEADS][64 * 40];
  __shared__ alignas(16) bf16 sVT[NHEADS][32 * 72];  // [head][chan][key 0..63] pad 72
  // union region: phase<=1: sA = LN tile [64][200]; phase 2-3: sP[head][64][72]; phase 4: attnout [64][200]
  __shared__ alignas(16) bf16 sU[NHEADS * 64 * 72];

  const int l  = threadIdx.x & 63;
  const int wv = threadIdx.x >> 6;       // wave id == head id
  const int b  = blockIdx.x >> 6;
  const int wi = blockIdx.x & 63;
  const int wh = wi >> 3, ww = wi & 7;

  bf16* sA = sU;   // [64][200]

  // ---- LN1 with shifted-window gather ----
  {
    const float w0 = n1w[l], w1 = n1w[l + 64], w2 = n1w[l + 128];
    const float c0 = n1b[l], c1 = n1b[l + 64], c2 = n1b[l + 128];
    for (int t = wv; t < 49; t += 6) {
      const int th = t / 7, tw = t - 7 * th;
      const int ho = (wh * 7 + th + 3) % 56;     // roll(-3) folded into gather
      const int wo = (ww * 7 + tw + 3) % 56;
      const float* xr = x + ((size_t)b * 3136 + ho * 56 + wo) * CD;
      float v0 = xr[l], v1 = xr[l + 64], v2 = xr[l + 128];
      float s  = v0 + v1 + v2;
      float ss = v0 * v0 + v1 * v1 + v2 * v2;
      #pragma unroll
      for (int off = 32; off; off >>= 1) { s += __shfl_xor(s, off); ss += __shfl_xor(ss, off); }
      const float mean = s * (1.f / 192.f);
      const float inv  = rsqrtf(ss * (1.f / 192.f) - mean * mean + 1e-5f);
      sA[t * 200 + l]       = (bf16)((v0 - mean) * inv * w0 + c0);
      sA[t * 200 + l + 64]  = (bf16)((v1 - mean) * inv * w1 + c1);
      sA[t * 200 + l + 128] = (bf16)((v2 - mean) * inv * w2 + c2);
    }
    for (int i = threadIdx.x; i < 15 * 200; i += 384) sA[49 * 200 + i] = (bf16)0.f;
  }
  __syncthreads();   // barrier 1: sA ready

  // ---- QKV GEMM: wave computes its head's 96 cols (q,k,v x 32) ----
  {
    const int h = wv;
    f32x4 acc[6][4] = {};
    #pragma unroll
    for (int ks = 0; ks < 6; ++ks) {
      const int k0 = ks * 32;
      bf16x8 af[4];
      #pragma unroll
      for (int mt = 0; mt < 4; ++mt) af[mt] = ld_frag(sA, mt * 16, k0, 200);
      #pragma unroll
      for (int nt = 0; nt < 6; ++nt) {
        const int col0 = (nt >> 1) * 192 + h * 32 + (nt & 1) * 16;
        const bf16x8 bfr = ld_frag(wtq, col0, k0, 192);
        #pragma unroll
        for (int mt = 0; mt < 4; ++mt) acc[nt][mt] = mfma16(af[mt], bfr, acc[nt][mt]);
      }
    }
    #pragma unroll
    for (int nt = 0; nt < 6; ++nt) {
      const int which = nt >> 1;
      const int c = (nt & 1) * 16 + (l & 15);             // channel within head
      const float bias = qkvb[which * 192 + h * 32 + c];
      #pragma unroll
      for (int mt = 0; mt < 4; ++mt)
        #pragma unroll
        for (int i = 0; i < 4; ++i) {
          const int r = mt * 16 + (l >> 4) * 4 + i;
          const float v = acc[nt][mt][i] + bias;
          if (which == 0)      sQ[h][r * 40 + c] = (bf16)(v * 0.17677669529663689f); // pre-scale q
          else if (which == 1) sK[h][r * 40 + c] = (bf16)v;
          else                 sVT[h][c * 72 + r] = (bf16)v;  // V transposed for PV B-frags
        }
    }
  }
  __syncthreads();   // barrier 2: sA dead -> sP region may be written

  // ---- scores + bias + mask + softmax (wave-local) ----
  bf16* sP = sU + wv * (64 * 72);
  {
    const int h = wv;
    f32x4 sc[4][4] = {};
    bf16x8 qf[4];
    #pragma unroll
    for (int mt = 0; mt < 4; ++mt) qf[mt] = ld_frag(sQ[h], mt * 16, 0, 40);
    #pragma unroll
    for (int nt = 0; nt < 4; ++nt) {
      const bf16x8 kf = ld_frag(sK[h], nt * 16, 0, 40);
      #pragma unroll
      for (int mt = 0; mt < 4; ++mt) sc[mt][nt] = mfma16(qf[mt], kf, sc[mt][nt]);
    }
    int kkv[4], khv[4], kwv[4], clk[4];
    #pragma unroll
    for (int nt = 0; nt < 4; ++nt) {
      kkv[nt] = nt * 16 + (l & 15);
      khv[nt] = kkv[nt] / 7; kwv[nt] = kkv[nt] - 7 * khv[nt];
      const int gh = wh * 7 + khv[nt], gw = ww * 7 + kwv[nt];
      clk[nt] = (gh < 49 ? 0 : (gh < 53 ? 1 : 2)) * 3 + (gw < 49 ? 0 : (gw < 53 ? 1 : 2));
    }
    #pragma unroll
    for (int mt = 0; mt < 4; ++mt)
      #pragma unroll
      for (int i = 0; i < 4; ++i) {
        const int r = mt * 16 + (l >> 4) * 4 + i;        // query token (rows same across 16-lane group)
        const int rh = r / 7, rw = r - 7 * rh;
        const int gh = wh * 7 + rh, gw = ww * 7 + rw;
        const int clr = (gh < 49 ? 0 : (gh < 53 ? 1 : 2)) * 3 + (gw < 49 ? 0 : (gw < 53 ? 1 : 2));
        float v[4];
        #pragma unroll
        for (int nt = 0; nt < 4; ++nt) {
          if (r < 49 && kkv[nt] < 49) {
            const int bidx = (rh - khv[nt] + 6) * 13 + (rw - kwv[nt] + 6);
            v[nt] = sc[mt][nt][i] + relb[bidx * 6 + h] + ((clr != clk[nt]) ? -100.f : 0.f);
          } else v[nt] = -1e30f;
        }
        float mx = fmaxf(fmaxf(v[0], v[1]), fmaxf(v[2], v[3]));
        #pragma unroll
        for (int off = 1; off < 16; off <<= 1) mx = fmaxf(mx, __shfl_xor(mx, off));
        float p[4], sum = 0.f;
        #pragma unroll
        for (int nt = 0; nt < 4; ++nt) { p[nt] = __expf(v[nt] - mx); sum += p[nt]; }
        #pragma unroll
        for (int off = 1; off < 16; off <<= 1) sum += __shfl_xor(sum, off);
        const float isum = 1.f / sum;
        #pragma unroll
        for (int nt = 0; nt < 4; ++nt)
          sP[r * 72 + nt * 16 + (l & 15)] = (bf16)(p[nt] * isum);
      }
  }

  // ---- PV ----
  f32x4 o[4][2] = {};
  #pragma unroll
  for (int ks = 0; ks < 2; ++ks) {
    const int k0 = ks * 32;
    bf16x8 pf[4];
    #pragma unroll
    for (int mt = 0; mt < 4; ++mt) pf[mt] = ld_frag(sP, mt * 16, k0, 72);
    #pragma unroll
    for (int nt = 0; nt < 2; ++nt) {
      const bf16x8 vf = ld_frag(sVT[wv], nt * 16, k0, 72);
      #pragma unroll
      for (int mt = 0; mt < 4; ++mt) o[mt][nt] = mfma16(pf[mt], vf, o[mt][nt]);
    }
  }
  __syncthreads();   // barrier 3: all sP reads done before attnout overwrites region
  {
    bf16* sAO = sU;  // [64][200]
    #pragma unroll
    for (int nt = 0; nt < 2; ++nt) {
      const int c = wv * 32 + nt * 16 + (l & 15);
      #pragma unroll
      for (int mt = 0; mt < 4; ++mt)
        #pragma unroll
        for (int i = 0; i < 4; ++i) {
          const int r = mt * 16 + (l >> 4) * 4 + i;
          sAO[r * 200 + c] = (bf16)o[mt][nt][i];
        }
    }
  }
  __syncthreads();   // barrier 4: attnout ready

  // ---- proj + residual, un-shift scatter ----
  {
    const bf16* sAO = sU;
    f32x4 po[4][2] = {};
    #pragma unroll
    for (int ks = 0; ks < 6; ++ks) {
      const int k0 = ks * 32;
      bf16x8 af[4];
      #pragma unroll
      for (int mt = 0; mt < 4; ++mt) af[mt] = ld_frag(sAO, mt * 16, k0, 200);
      #pragma unroll
      for (int nt = 0; nt < 2; ++nt) {
        const bf16x8 bfr = ld_frag(wtp, wv * 32 + nt * 16, k0, 192);
        #pragma unroll
        for (int mt = 0; mt < 4; ++mt) po[mt][nt] = mfma16(af[mt], bfr, po[mt][nt]);
      }
    }
    #pragma unroll
    for (int mt = 0; mt < 4; ++mt)
      #pragma unroll
      for (int i = 0; i < 4; ++i) {
        const int r = mt * 16 + (l >> 4) * 4 + i;
        if (r < 49) {
          const int th = r / 7, tw = r - 7 * th;
          const int ho = (wh * 7 + th + 3) % 56;
          const int wo = (ww * 7 + tw + 3) % 56;
          const size_t base = ((size_t)b * 3136 + ho * 56 + wo) * CD;
          #pragma unroll
          for (int nt = 0; nt < 2; ++nt) {
            const int c = wv * 32 + nt * 16 + (l & 15);
            out[base + c] = po[mt][nt][i] + projb[c] + x[base + c];
          }
        }
      }
  }
}

// ---------------- MLP: 32 tokens/block, LN2 -> FC1+GELU(LDS) -> FC2 + residual, in-place ----
__global__ __launch_bounds__(256, 2)
void swin_mlp_kernel(const float* __restrict__ n2w, const float* __restrict__ n2b,
                     const bf16* __restrict__ wt1, const float* __restrict__ fb1,
                     const bf16* __restrict__ wt2, const float* __restrict__ fb2,
                     float* __restrict__ io)
{
  __shared__ alignas(16) bf16 sA[32 * 200];
  __shared__ alignas(16) bf16 sH[32 * 776];
  const int l  = threadIdx.x & 63;
  const int wv = threadIdx.x >> 6;
  const size_t t0 = (size_t)blockIdx.x * 32;

  {
    const float w0 = n2w[l], w1 = n2w[l + 64], w2 = n2w[l + 128];
    const float c0 = n2b[l], c1 = n2b[l + 64], c2 = n2b[l + 128];
    for (int t = wv; t < 32; t += 4) {
      const float* xr = io + (t0 + t) * CD;
      float v0 = xr[l], v1 = xr[l + 64], v2 = xr[l + 128];
      float s  = v0 + v1 + v2;
      float ss = v0 * v0 + v1 * v1 + v2 * v2;
      #pragma unroll
      for (int off = 32; off; off >>= 1) { s += __shfl_xor(s, off); ss += __shfl_xor(ss, off); }
      const float mean = s * (1.f / 192.f);
      const float inv  = rsqrtf(ss * (1.f / 192.f) - mean * mean + 1e-5f);
      sA[t * 200 + l]       = (bf16)((v0 - mean) * inv * w0 + c0);
      sA[t * 200 + l + 64]  = (bf16)((v1 - mean) * inv * w1 + c1);
      sA[t * 200 + l + 128] = (bf16)((v2 - mean) * inv * w2 + c2);
    }
  }
  __syncthreads();

  { // FC1 + GELU (exact erf)
    f32x4 acc[12][2] = {};
    #pragma unroll
    for (int ks = 0; ks < 6; ++ks) {
      const int k0 = ks * 32;
      bf16x8 af[2];
      af[0] = ld_frag(sA, 0, k0, 200);
      af[1] = ld_frag(sA, 16, k0, 200);
      #pragma unroll
      for (int nt = 0; nt < 12; ++nt) {
        const bf16x8 bfr = ld_frag(wt1, wv * 192 + nt * 16, k0, 192);
        acc[nt][0] = mfma16(af[0], bfr, acc[nt][0]);
        acc[nt][1] = mfma16(af[1], bfr, acc[nt][1]);
      }
    }
    #pragma unroll
    for (int nt = 0; nt < 12; ++nt) {
      const int col = wv * 192 + nt * 16 + (l & 15);
      const float bias = fb1[col];
      #pragma unroll
      for (int mt = 0; mt < 2; ++mt)
        #pragma unroll
        for (int i = 0; i < 4; ++i) {
          const int r = mt * 16 + (l >> 4) * 4 + i;
          const float v = acc[nt][mt][i] + bias;
          const float g = 0.5f * v * (1.f + erff(v * 0.70710678118654752f));
          sH[r * 776 + col] = (bf16)g;
        }
    }
  }
  __syncthreads();

  { // FC2 + residual (in-place on io)
    f32x4 acc[3][2] = {};
    for (int ks = 0; ks < 24; ++ks) {
      const int k0 = ks * 32;
      bf16x8 af[2];
      af[0] = ld_frag(sH, 0, k0, 776);
      af[1] = ld_frag(sH, 16, k0, 776);
      #pragma unroll
      for (int nt = 0; nt < 3; ++nt) {
        const bf16x8 bfr = ld_frag(wt2, wv * 48 + nt * 16, k0, 768);
        acc[nt][0] = mfma16(af[0], bfr, acc[nt][0]);
        acc[nt][1] = mfma16(af[1], bfr, acc[nt][1]);
      }
    }
    #pragma unroll
    for (int nt = 0; nt < 3; ++nt) {
      const int col = wv * 48 + nt * 16 + (l & 15);
      const float bias = fb2[col];
      #pragma unroll
      for (int mt = 0; mt < 2; ++mt)
        #pragma unroll
        for (int i = 0; i < 4; ++i) {
          const int r = mt * 16 + (l >> 4) * 4 + i;
          const size_t idx = (t0 + r) * CD + col;
          io[idx] = acc[nt][mt][i] + bias + io[idx];
        }
    }
  }
}

extern "C" void kernel_launch(void* const* d_in, const int* in_sizes, int n_in,
                              void* d_out, int out_size, void* d_ws, size_t ws_size,
                              hipStream_t stream) {
  const float* x     = (const float*)d_in[0];
  const float* n1w   = (const float*)d_in[1];
  const float* n1b   = (const float*)d_in[2];
  const float* qkvw  = (const float*)d_in[3];
  const float* qkvb  = (const float*)d_in[4];
  const float* projw = (const float*)d_in[5];
  const float* projb = (const float*)d_in[6];
  const float* relb  = (const float*)d_in[7];
  const float* n2w   = (const float*)d_in[8];
  const float* n2b   = (const float*)d_in[9];
  const float* f1w   = (const float*)d_in[10];
  const float* f1b   = (const float*)d_in[11];
  const float* f2w   = (const float*)d_in[12];
  const float* f2b   = (const float*)d_in[13];

  char* ws = (char*)d_ws;
  bf16* wtq = (bf16*)(ws + 0);        // [576][192]
  bf16* wtp = (bf16*)(ws + 221184);   // [192][192]
  bf16* wt1 = (bf16*)(ws + 294912);   // [768][192]
  bf16* wt2 = (bf16*)(ws + 589824);   // [192][768]

  prep_wt<<<(192 * 576 + 255) / 256, 256, 0, stream>>>(qkvw, wtq, 192, 576);
  prep_wt<<<(192 * 192 + 255) / 256, 256, 0, stream>>>(projw, wtp, 192, 192);
  prep_wt<<<(192 * 768 + 255) / 256, 256, 0, stream>>>(f1w, wt1, 192, 768);
  prep_wt<<<(768 * 192 + 255) / 256, 256, 0, stream>>>(f2w, wt2, 768, 192);

  swin_attn_kernel<<<4096, 384, 0, stream>>>(x, n1w, n1b, wtq, qkvb, wtp, projb, relb, (float*)d_out);
  swin_mlp_kernel<<<6272, 256, 0, stream>>>(n2w, n2b, wt1, f1b, wt2, f2b, (float*)d_out);
}

// Round 2
// 944.721 us; speedup vs baseline: 1.0337x; 1.0337x over previous
//
#include <hip/hip_runtime.h>
#include <hip/hip_bf16.h>
#include <math.h>

typedef __bf16 bf16;
typedef bf16  bf16x8 __attribute__((ext_vector_type(8)));
typedef float f32x4  __attribute__((ext_vector_type(4)));

#define CD 192
#define NHEADS 6

// One fragment convention for BOTH A and B operands of mfma_f32_16x16x32_bf16:
// lane l supplies (row/col) = r0 + (l&15), k = k0 + 8*(l>>4) + j  (8 contiguous bf16 = 16B).
// Any deviation of the HW k-map cancels because A and B use the identical map.
__device__ __forceinline__ bf16x8 ld_frag(const bf16* p, int r0, int k0, int ld) {
  const int l = threadIdx.x & 63;
  return *reinterpret_cast<const bf16x8*>(p + (r0 + (l & 15)) * ld + (k0 + 8 * (l >> 4)));
}

__device__ __forceinline__ f32x4 mfma16(bf16x8 a, bf16x8 b, f32x4 c) {
  return __builtin_amdgcn_mfma_f32_16x16x32_bf16(a, b, c, 0, 0, 0);
}

// tanh-approx GELU: max abs err ~1e-3, ~6 VALU ops vs ~25 for erff.
__device__ __forceinline__ float gelu_f(float v) {
  return v / (1.f + __expf(-1.5957691216057308f * (v + 0.044715f * v * v * v)));
}

// ---------------- weight transpose + bf16 convert: dst[n*K+k] = src[k*N+n] ----------------
__global__ void prep_wt(const float* __restrict__ src, bf16* __restrict__ dst, int K, int N) {
  int i = blockIdx.x * 256 + threadIdx.x;
  if (i < K * N) {
    int k = i / N, n = i - k * N;
    dst[n * K + k] = (bf16)src[i];
  }
}

// ---------------- attention block: 1 block = 1 window (b, wh, ww); 6 waves = 6 heads -------
__global__ __launch_bounds__(384, 1)
void swin_attn_kernel(const float* __restrict__ x,
                      const float* __restrict__ n1w, const float* __restrict__ n1b,
                      const bf16* __restrict__ wtq, const float* __restrict__ qkvb,
                      const bf16* __restrict__ wtp, const float* __restrict__ projb,
                      const float* __restrict__ relb,
                      float* __restrict__ out)
{
  __shared__ alignas(16) bf16 sQ[NHEADS][64 * 40];   // [head][row 0..63][chan 0..31] pad 40
  __shared__ alignas(16) bf16 sK[NHEADS][64 * 40];
  __shared__ alignas(16) bf16 sVT[NHEADS][32 * 72];  // [head][chan][key 0..63] pad 72
  // union region: phase<=1: sA = LN tile [64][200]; phase 2-3: sP[head][64][72]; phase 4: attnout [64][200]
  __shared__ alignas(16) bf16 sU[NHEADS * 64 * 72];

  const int l  = threadIdx.x & 63;
  const int wv = threadIdx.x >> 6;       // wave id == head id
  const int b  = blockIdx.x >> 6;
  const int wi = blockIdx.x & 63;
  const int wh = wi >> 3, ww = wi & 7;

  bf16* sA = sU;   // [64][200]

  // ---- LN1 with shifted-window gather ----
  {
    const float w0 = n1w[l], w1 = n1w[l + 64], w2 = n1w[l + 128];
    const float c0 = n1b[l], c1 = n1b[l + 64], c2 = n1b[l + 128];
    for (int t = wv; t < 49; t += 6) {
      const int th = t / 7, tw = t - 7 * th;
      const int ho = (wh * 7 + th + 3) % 56;     // roll(-3) folded into gather
      const int wo = (ww * 7 + tw + 3) % 56;
      const float* xr = x + ((size_t)b * 3136 + ho * 56 + wo) * CD;
      float v0 = xr[l], v1 = xr[l + 64], v2 = xr[l + 128];
      float s  = v0 + v1 + v2;
      float ss = v0 * v0 + v1 * v1 + v2 * v2;
      #pragma unroll
      for (int off = 32; off; off >>= 1) { s += __shfl_xor(s, off); ss += __shfl_xor(ss, off); }
      const float mean = s * (1.f / 192.f);
      const float inv  = rsqrtf(ss * (1.f / 192.f) - mean * mean + 1e-5f);
      sA[t * 200 + l]       = (bf16)((v0 - mean) * inv * w0 + c0);
      sA[t * 200 + l + 64]  = (bf16)((v1 - mean) * inv * w1 + c1);
      sA[t * 200 + l + 128] = (bf16)((v2 - mean) * inv * w2 + c2);
    }
    for (int i = threadIdx.x; i < 15 * 200; i += 384) sA[49 * 200 + i] = (bf16)0.f;
  }
  __syncthreads();   // barrier 1: sA ready

  // ---- QKV GEMM: wave computes its head's 96 cols (q,k,v x 32) ----
  {
    const int h = wv;
    f32x4 acc[6][4] = {};
    #pragma unroll
    for (int ks = 0; ks < 6; ++ks) {
      const int k0 = ks * 32;
      bf16x8 af[4];
      #pragma unroll
      for (int mt = 0; mt < 4; ++mt) af[mt] = ld_frag(sA, mt * 16, k0, 200);
      #pragma unroll
      for (int nt = 0; nt < 6; ++nt) {
        const int col0 = (nt >> 1) * 192 + h * 32 + (nt & 1) * 16;
        const bf16x8 bfr = ld_frag(wtq, col0, k0, 192);
        #pragma unroll
        for (int mt = 0; mt < 4; ++mt) acc[nt][mt] = mfma16(af[mt], bfr, acc[nt][mt]);
      }
    }
    #pragma unroll
    for (int nt = 0; nt < 6; ++nt) {
      const int which = nt >> 1;
      const int c = (nt & 1) * 16 + (l & 15);             // channel within head
      const float bias = qkvb[which * 192 + h * 32 + c];
      #pragma unroll
      for (int mt = 0; mt < 4; ++mt)
        #pragma unroll
        for (int i = 0; i < 4; ++i) {
          const int r = mt * 16 + (l >> 4) * 4 + i;
          const float v = acc[nt][mt][i] + bias;
          if (which == 0)      sQ[h][r * 40 + c] = (bf16)(v * 0.17677669529663689f); // pre-scale q
          else if (which == 1) sK[h][r * 40 + c] = (bf16)v;
          else                 sVT[h][c * 72 + r] = (bf16)v;  // V transposed for PV B-frags
        }
    }
  }
  __syncthreads();   // barrier 2: sA dead -> sP region may be written

  // ---- scores + bias + mask + softmax (wave-local) ----
  bf16* sP = sU + wv * (64 * 72);
  {
    const int h = wv;
    f32x4 sc[4][4] = {};
    bf16x8 qf[4];
    #pragma unroll
    for (int mt = 0; mt < 4; ++mt) qf[mt] = ld_frag(sQ[h], mt * 16, 0, 40);
    #pragma unroll
    for (int nt = 0; nt < 4; ++nt) {
      const bf16x8 kf = ld_frag(sK[h], nt * 16, 0, 40);
      #pragma unroll
      for (int mt = 0; mt < 4; ++mt) sc[mt][nt] = mfma16(qf[mt], kf, sc[mt][nt]);
    }
    int kkv[4], khv[4], kwv[4], clk[4];
    #pragma unroll
    for (int nt = 0; nt < 4; ++nt) {
      kkv[nt] = nt * 16 + (l & 15);
      khv[nt] = kkv[nt] / 7; kwv[nt] = kkv[nt] - 7 * khv[nt];
      const int gh = wh * 7 + khv[nt], gw = ww * 7 + kwv[nt];
      clk[nt] = (gh < 49 ? 0 : (gh < 53 ? 1 : 2)) * 3 + (gw < 49 ? 0 : (gw < 53 ? 1 : 2));
    }
    #pragma unroll
    for (int mt = 0; mt < 4; ++mt)
      #pragma unroll
      for (int i = 0; i < 4; ++i) {
        const int r = mt * 16 + (l >> 4) * 4 + i;        // query token (rows same across 16-lane group)
        const int rh = r / 7, rw = r - 7 * rh;
        const int gh = wh * 7 + rh, gw = ww * 7 + rw;
        const int clr = (gh < 49 ? 0 : (gh < 53 ? 1 : 2)) * 3 + (gw < 49 ? 0 : (gw < 53 ? 1 : 2));
        float v[4];
        #pragma unroll
        for (int nt = 0; nt < 4; ++nt) {
          if (r < 49 && kkv[nt] < 49) {
            const int bidx = (rh - khv[nt] + 6) * 13 + (rw - kwv[nt] + 6);
            v[nt] = sc[mt][nt][i] + relb[bidx * 6 + h] + ((clr != clk[nt]) ? -100.f : 0.f);
          } else v[nt] = -1e30f;
        }
        float mx = fmaxf(fmaxf(v[0], v[1]), fmaxf(v[2], v[3]));
        #pragma unroll
        for (int off = 1; off < 16; off <<= 1) mx = fmaxf(mx, __shfl_xor(mx, off));
        float p[4], sum = 0.f;
        #pragma unroll
        for (int nt = 0; nt < 4; ++nt) { p[nt] = __expf(v[nt] - mx); sum += p[nt]; }
        #pragma unroll
        for (int off = 1; off < 16; off <<= 1) sum += __shfl_xor(sum, off);
        const float isum = 1.f / sum;
        #pragma unroll
        for (int nt = 0; nt < 4; ++nt)
          sP[r * 72 + nt * 16 + (l & 15)] = (bf16)(p[nt] * isum);
      }
  }

  // ---- PV ----
  f32x4 o[4][2] = {};
  #pragma unroll
  for (int ks = 0; ks < 2; ++ks) {
    const int k0 = ks * 32;
    bf16x8 pf[4];
    #pragma unroll
    for (int mt = 0; mt < 4; ++mt) pf[mt] = ld_frag(sP, mt * 16, k0, 72);
    #pragma unroll
    for (int nt = 0; nt < 2; ++nt) {
      const bf16x8 vf = ld_frag(sVT[wv], nt * 16, k0, 72);
      #pragma unroll
      for (int mt = 0; mt < 4; ++mt) o[mt][nt] = mfma16(pf[mt], vf, o[mt][nt]);
    }
  }
  __syncthreads();   // barrier 3: all sP reads done before attnout overwrites region
  {
    bf16* sAO = sU;  // [64][200]
    #pragma unroll
    for (int nt = 0; nt < 2; ++nt) {
      const int c = wv * 32 + nt * 16 + (l & 15);
      #pragma unroll
      for (int mt = 0; mt < 4; ++mt)
        #pragma unroll
        for (int i = 0; i < 4; ++i) {
          const int r = mt * 16 + (l >> 4) * 4 + i;
          sAO[r * 200 + c] = (bf16)o[mt][nt][i];
        }
    }
  }
  __syncthreads();   // barrier 4: attnout ready

  // ---- proj + residual, un-shift scatter ----
  {
    const bf16* sAO = sU;
    f32x4 po[4][2] = {};
    #pragma unroll
    for (int ks = 0; ks < 6; ++ks) {
      const int k0 = ks * 32;
      bf16x8 af[4];
      #pragma unroll
      for (int mt = 0; mt < 4; ++mt) af[mt] = ld_frag(sAO, mt * 16, k0, 200);
      #pragma unroll
      for (int nt = 0; nt < 2; ++nt) {
        const bf16x8 bfr = ld_frag(wtp, wv * 32 + nt * 16, k0, 192);
        #pragma unroll
        for (int mt = 0; mt < 4; ++mt) po[mt][nt] = mfma16(af[mt], bfr, po[mt][nt]);
      }
    }
    #pragma unroll
    for (int mt = 0; mt < 4; ++mt)
      #pragma unroll
      for (int i = 0; i < 4; ++i) {
        const int r = mt * 16 + (l >> 4) * 4 + i;
        if (r < 49) {
          const int th = r / 7, tw = r - 7 * th;
          const int ho = (wh * 7 + th + 3) % 56;
          const int wo = (ww * 7 + tw + 3) % 56;
          const size_t base = ((size_t)b * 3136 + ho * 56 + wo) * CD;
          #pragma unroll
          for (int nt = 0; nt < 2; ++nt) {
            const int c = wv * 32 + nt * 16 + (l & 15);
            out[base + c] = po[mt][nt][i] + projb[c] + x[base + c];
          }
        }
      }
  }
}

// ---------------- MLP v2: 64 tokens/block, 8 waves, K-streamed FC1->GELU->FC2 fusion --------
// hidden processed in 6 chunks of 128, double-buffered in LDS; FC2 accumulates in VGPRs.
// LDS = 64*200*2 + 2*64*136*2 = 60.4 KB -> 2 blocks/CU (16 waves/CU).
__global__ __launch_bounds__(512, 4)
void swin_mlp_kernel(const float* __restrict__ n2w, const float* __restrict__ n2b,
                     const bf16* __restrict__ wt1, const float* __restrict__ fb1,
                     const bf16* __restrict__ wt2, const float* __restrict__ fb2,
                     float* __restrict__ io)
{
  __shared__ alignas(16) bf16 sA[64 * 200];       // LN2 output [64 tok][192 ch]
  __shared__ alignas(16) bf16 sH[2][64 * 136];    // hidden chunk dbuf [64 tok][128]
  const int l  = threadIdx.x & 63;
  const int wv = threadIdx.x >> 6;   // 0..7
  const int wr = wv & 1;             // M-half: rows wr*32..wr*32+31
  const int wc = wv >> 1;            // 0..3: N-quarter
  const size_t t0 = (size_t)blockIdx.x * 64;

  // ---- LN2 ----
  {
    const float w0 = n2w[l], w1 = n2w[l + 64], w2 = n2w[l + 128];
    const float c0 = n2b[l], c1 = n2b[l + 64], c2 = n2b[l + 128];
    for (int t = wv; t < 64; t += 8) {
      const float* xr = io + (t0 + t) * CD;
      float v0 = xr[l], v1 = xr[l + 64], v2 = xr[l + 128];
      float s  = v0 + v1 + v2;
      float ss = v0 * v0 + v1 * v1 + v2 * v2;
      #pragma unroll
      for (int off = 32; off; off >>= 1) { s += __shfl_xor(s, off); ss += __shfl_xor(ss, off); }
      const float mean = s * (1.f / 192.f);
      const float inv  = rsqrtf(ss * (1.f / 192.f) - mean * mean + 1e-5f);
      sA[t * 200 + l]       = (bf16)((v0 - mean) * inv * w0 + c0);
      sA[t * 200 + l + 64]  = (bf16)((v1 - mean) * inv * w1 + c1);
      sA[t * 200 + l + 128] = (bf16)((v2 - mean) * inv * w2 + c2);
    }
  }
  __syncthreads();

  f32x4 oacc[2][3] = {};   // FC2 out: rows wr*32+mt*16, cols wc*48+nt*16 (persistent)

  for (int kc = 0; kc < 6; ++kc) {
    bf16* hb = sH[kc & 1];
    // ---- FC1 chunk: h[64][kc*128 .. +128]; wave computes rows wr*32..+32, cols wc*32..+32
    {
      f32x4 acc[2][2] = {};
      #pragma unroll
      for (int ks = 0; ks < 6; ++ks) {
        const int k0 = ks * 32;
        bf16x8 af0 = ld_frag(sA, wr * 32,      k0, 200);
        bf16x8 af1 = ld_frag(sA, wr * 32 + 16, k0, 200);
        #pragma unroll
        for (int nt = 0; nt < 2; ++nt) {
          const bf16x8 bfr = ld_frag(wt1, kc * 128 + wc * 32 + nt * 16, k0, 192);
          acc[0][nt] = mfma16(af0, bfr, acc[0][nt]);
          acc[1][nt] = mfma16(af1, bfr, acc[1][nt]);
        }
      }
      #pragma unroll
      for (int nt = 0; nt < 2; ++nt) {
        const int col = wc * 32 + nt * 16 + (l & 15);
        const float bias = fb1[kc * 128 + col];
        #pragma unroll
        for (int mt = 0; mt < 2; ++mt)
          #pragma unroll
          for (int i = 0; i < 4; ++i) {
            const int r = wr * 32 + mt * 16 + (l >> 4) * 4 + i;
            hb[r * 136 + col] = (bf16)gelu_f(acc[mt][nt][i] + bias);
          }
      }
    }
    __syncthreads();   // hb ready; dbuf makes this the ONLY barrier per chunk
    // ---- FC2 accumulate: out[64][192] += hb[64][128] x wt2-chunk
    #pragma unroll
    for (int ks = 0; ks < 4; ++ks) {
      const int k0 = ks * 32;
      bf16x8 af0 = ld_frag(hb, wr * 32,      k0, 136);
      bf16x8 af1 = ld_frag(hb, wr * 32 + 16, k0, 136);
      #pragma unroll
      for (int nt = 0; nt < 3; ++nt) {
        const bf16x8 bfr = ld_frag(wt2, wc * 48 + nt * 16, kc * 128 + k0, 768);
        oacc[0][nt] = mfma16(af0, bfr, oacc[0][nt]);
        oacc[1][nt] = mfma16(af1, bfr, oacc[1][nt]);
      }
    }
  }

  // ---- epilogue: bias + residual, in-place ----
  #pragma unroll
  for (int nt = 0; nt < 3; ++nt) {
    const int col = wc * 48 + nt * 16 + (l & 15);
    const float bias = fb2[col];
    #pragma unroll
    for (int mt = 0; mt < 2; ++mt)
      #pragma unroll
      for (int i = 0; i < 4; ++i) {
        const int r = wr * 32 + mt * 16 + (l >> 4) * 4 + i;
        const size_t idx = (t0 + r) * CD + col;
        io[idx] = oacc[mt][nt][i] + bias + io[idx];
      }
  }
}

extern "C" void kernel_launch(void* const* d_in, const int* in_sizes, int n_in,
                              void* d_out, int out_size, void* d_ws, size_t ws_size,
                              hipStream_t stream) {
  const float* x     = (const float*)d_in[0];
  const float* n1w   = (const float*)d_in[1];
  const float* n1b   = (const float*)d_in[2];
  const float* qkvw  = (const float*)d_in[3];
  const float* qkvb  = (const float*)d_in[4];
  const float* projw = (const float*)d_in[5];
  const float* projb = (const float*)d_in[6];
  const float* relb  = (const float*)d_in[7];
  const float* n2w   = (const float*)d_in[8];
  const float* n2b   = (const float*)d_in[9];
  const float* f1w   = (const float*)d_in[10];
  const float* f1b   = (const float*)d_in[11];
  const float* f2w   = (const float*)d_in[12];
  const float* f2b   = (const float*)d_in[13];

  char* ws = (char*)d_ws;
  bf16* wtq = (bf16*)(ws + 0);        // [576][192]
  bf16* wtp = (bf16*)(ws + 221184);   // [192][192]
  bf16* wt1 = (bf16*)(ws + 294912);   // [768][192]
  bf16* wt2 = (bf16*)(ws + 589824);   // [192][768]

  prep_wt<<<(192 * 576 + 255) / 256, 256, 0, stream>>>(qkvw, wtq, 192, 576);
  prep_wt<<<(192 * 192 + 255) / 256, 256, 0, stream>>>(projw, wtp, 192, 192);
  prep_wt<<<(192 * 768 + 255) / 256, 256, 0, stream>>>(f1w, wt1, 192, 768);
  prep_wt<<<(768 * 192 + 255) / 256, 256, 0, stream>>>(f2w, wt2, 768, 192);

  swin_attn_kernel<<<4096, 384, 0, stream>>>(x, n1w, n1b, wtq, qkvb, wtp, projb, relb, (float*)d_out);
  swin_mlp_kernel<<<3136, 512, 0, stream>>>(n2w, n2b, wt1, f1b, wt2, f2b, (float*)d_out);
}

// Round 3
// 676.837 us; speedup vs baseline: 1.4428x; 1.3958x over previous
//
#include <hip/hip_runtime.h>
#include <hip/hip_bf16.h>
#include <math.h>

typedef __bf16 bf16;
typedef bf16  bf16x8 __attribute__((ext_vector_type(8)));
typedef float f32x4  __attribute__((ext_vector_type(4)));

#define CD 192
#define NHEADS 6

// One fragment convention for BOTH A and B operands of mfma_f32_16x16x32_bf16:
// lane l supplies (row/col) = r0 + (l&15), k = k0 + 8*(l>>4) + j  (8 contiguous bf16 = 16B).
// Any deviation of the HW k-map cancels because A and B use the identical map.
__device__ __forceinline__ bf16x8 ld_frag(const bf16* p, int r0, int k0, int ld) {
  const int l = threadIdx.x & 63;
  return *reinterpret_cast<const bf16x8*>(p + (r0 + (l & 15)) * ld + (k0 + 8 * (l >> 4)));
}

__device__ __forceinline__ f32x4 mfma16(bf16x8 a, bf16x8 b, f32x4 c) {
  return __builtin_amdgcn_mfma_f32_16x16x32_bf16(a, b, c, 0, 0, 0);
}

// tanh-approx GELU: max abs err ~1e-3, ~6 VALU ops vs ~25 for erff.
__device__ __forceinline__ float gelu_f(float v) {
  return v / (1.f + __expf(-1.5957691216057308f * (v + 0.044715f * v * v * v)));
}

// ---------------- weight pack: fragment-major layout --------------------------------------
// src is [K][N] row-major (as the reference weights). For n-tile ng (16 wide) and k-tile kt
// (32 deep), lane l's bf16x8 fragment (n = ng*16+(l&15), k = kt*32+8*(l>>4)+j) is stored
// contiguously at dst[((ng*(K/32)+kt)*64 + l)*8]. A wave's B-load = 1KB contiguous.
__global__ void prep_pack(const float* __restrict__ src, bf16* __restrict__ dst, int K, int N) {
  const int t = blockIdx.x * 256 + threadIdx.x;
  const int ktiles = K >> 5;
  const int total = (N >> 4) * ktiles * 64;
  if (t >= total) return;
  const int l  = t & 63;
  const int r  = t >> 6;
  const int kt = r % ktiles;
  const int ng = r / ktiles;
  const int n  = ng * 16 + (l & 15);
  const int k0 = kt * 32 + 8 * (l >> 4);
  bf16x8 v;
  #pragma unroll
  for (int j = 0; j < 8; ++j) v[j] = (bf16)src[(size_t)(k0 + j) * N + n];
  *(reinterpret_cast<bf16x8*>(dst) + t) = v;
}

// ---------------- attention block: 1 block = 1 window (b, wh, ww); 6 waves = 6 heads -------
__global__ __launch_bounds__(384, 1)
void swin_attn_kernel(const float* __restrict__ x,
                      const float* __restrict__ n1w, const float* __restrict__ n1b,
                      const bf16* __restrict__ wqf, const float* __restrict__ qkvb,
                      const bf16* __restrict__ wpf, const float* __restrict__ projb,
                      const float* __restrict__ relb,
                      float* __restrict__ out)
{
  __shared__ alignas(16) bf16 sQ[NHEADS][64 * 40];   // [head][row 0..63][chan 0..31] pad 40
  __shared__ alignas(16) bf16 sK[NHEADS][64 * 40];
  __shared__ alignas(16) bf16 sVT[NHEADS][32 * 72];  // [head][chan][key 0..63] pad 72
  // union region: phase<=1: sA = LN tile [64][200]; phase 2-3: sP[head][64][72]; phase 4: attnout [64][200]
  __shared__ alignas(16) bf16 sU[NHEADS * 64 * 72];

  const int l  = threadIdx.x & 63;
  const int wv = threadIdx.x >> 6;       // wave id == head id
  const int b  = blockIdx.x >> 6;
  const int wi = blockIdx.x & 63;
  const int wh = wi >> 3, ww = wi & 7;

  bf16* sA = sU;   // [64][200]

  // ---- LN1 with shifted-window gather ----
  {
    const float w0 = n1w[l], w1 = n1w[l + 64], w2 = n1w[l + 128];
    const float c0 = n1b[l], c1 = n1b[l + 64], c2 = n1b[l + 128];
    for (int t = wv; t < 49; t += 6) {
      const int th = t / 7, tw = t - 7 * th;
      const int ho = (wh * 7 + th + 3) % 56;     // roll(-3) folded into gather
      const int wo = (ww * 7 + tw + 3) % 56;
      const float* xr = x + ((size_t)b * 3136 + ho * 56 + wo) * CD;
      float v0 = xr[l], v1 = xr[l + 64], v2 = xr[l + 128];
      float s  = v0 + v1 + v2;
      float ss = v0 * v0 + v1 * v1 + v2 * v2;
      #pragma unroll
      for (int off = 32; off; off >>= 1) { s += __shfl_xor(s, off); ss += __shfl_xor(ss, off); }
      const float mean = s * (1.f / 192.f);
      const float inv  = rsqrtf(ss * (1.f / 192.f) - mean * mean + 1e-5f);
      sA[t * 200 + l]       = (bf16)((v0 - mean) * inv * w0 + c0);
      sA[t * 200 + l + 64]  = (bf16)((v1 - mean) * inv * w1 + c1);
      sA[t * 200 + l + 128] = (bf16)((v2 - mean) * inv * w2 + c2);
    }
    for (int i = threadIdx.x; i < 15 * 200; i += 384) sA[49 * 200 + i] = (bf16)0.f;
  }
  __syncthreads();   // barrier 1: sA ready

  // ---- QKV GEMM: wave computes its head's 96 cols (q,k,v x 32) ----
  {
    const int h = wv;
    const bf16x8* bq = reinterpret_cast<const bf16x8*>(wqf) + l;
    f32x4 acc[6][4] = {};
    #pragma unroll
    for (int ks = 0; ks < 6; ++ks) {
      const int k0 = ks * 32;
      bf16x8 af[4];
      #pragma unroll
      for (int mt = 0; mt < 4; ++mt) af[mt] = ld_frag(sA, mt * 16, k0, 200);
      #pragma unroll
      for (int nt = 0; nt < 6; ++nt) {
        const int ng = (nt >> 1) * 12 + h * 2 + (nt & 1);    // col-tile of [576]
        const bf16x8 bfr = bq[(ng * 6 + ks) * 64];
        #pragma unroll
        for (int mt = 0; mt < 4; ++mt) acc[nt][mt] = mfma16(af[mt], bfr, acc[nt][mt]);
      }
    }
    #pragma unroll
    for (int nt = 0; nt < 6; ++nt) {
      const int which = nt >> 1;
      const int c = (nt & 1) * 16 + (l & 15);             // channel within head
      const float bias = qkvb[which * 192 + h * 32 + c];
      #pragma unroll
      for (int mt = 0; mt < 4; ++mt)
        #pragma unroll
        for (int i = 0; i < 4; ++i) {
          const int r = mt * 16 + (l >> 4) * 4 + i;
          const float v = acc[nt][mt][i] + bias;
          if (which == 0)      sQ[h][r * 40 + c] = (bf16)(v * 0.17677669529663689f); // pre-scale q
          else if (which == 1) sK[h][r * 40 + c] = (bf16)v;
          else                 sVT[h][c * 72 + r] = (bf16)v;  // V transposed for PV B-frags
        }
    }
  }
  __syncthreads();   // barrier 2: sA dead -> sP region may be written

  // ---- scores + bias + mask + softmax (wave-local) ----
  bf16* sP = sU + wv * (64 * 72);
  {
    const int h = wv;
    f32x4 sc[4][4] = {};
    bf16x8 qf[4];
    #pragma unroll
    for (int mt = 0; mt < 4; ++mt) qf[mt] = ld_frag(sQ[h], mt * 16, 0, 40);
    #pragma unroll
    for (int nt = 0; nt < 4; ++nt) {
      const bf16x8 kf = ld_frag(sK[h], nt * 16, 0, 40);
      #pragma unroll
      for (int mt = 0; mt < 4; ++mt) sc[mt][nt] = mfma16(qf[mt], kf, sc[mt][nt]);
    }
    int kkv[4], khv[4], kwv[4], clk[4];
    #pragma unroll
    for (int nt = 0; nt < 4; ++nt) {
      kkv[nt] = nt * 16 + (l & 15);
      khv[nt] = kkv[nt] / 7; kwv[nt] = kkv[nt] - 7 * khv[nt];
      const int gh = wh * 7 + khv[nt], gw = ww * 7 + kwv[nt];
      clk[nt] = (gh < 49 ? 0 : (gh < 53 ? 1 : 2)) * 3 + (gw < 49 ? 0 : (gw < 53 ? 1 : 2));
    }
    #pragma unroll
    for (int mt = 0; mt < 4; ++mt)
      #pragma unroll
      for (int i = 0; i < 4; ++i) {
        const int r = mt * 16 + (l >> 4) * 4 + i;        // query token (rows same across 16-lane group)
        const int rh = r / 7, rw = r - 7 * rh;
        const int gh = wh * 7 + rh, gw = ww * 7 + rw;
        const int clr = (gh < 49 ? 0 : (gh < 53 ? 1 : 2)) * 3 + (gw < 49 ? 0 : (gw < 53 ? 1 : 2));
        float v[4];
        #pragma unroll
        for (int nt = 0; nt < 4; ++nt) {
          if (r < 49 && kkv[nt] < 49) {
            const int bidx = (rh - khv[nt] + 6) * 13 + (rw - kwv[nt] + 6);
            v[nt] = sc[mt][nt][i] + relb[bidx * 6 + h] + ((clr != clk[nt]) ? -100.f : 0.f);
          } else v[nt] = -1e30f;
        }
        float mx = fmaxf(fmaxf(v[0], v[1]), fmaxf(v[2], v[3]));
        #pragma unroll
        for (int off = 1; off < 16; off <<= 1) mx = fmaxf(mx, __shfl_xor(mx, off));
        float p[4], sum = 0.f;
        #pragma unroll
        for (int nt = 0; nt < 4; ++nt) { p[nt] = __expf(v[nt] - mx); sum += p[nt]; }
        #pragma unroll
        for (int off = 1; off < 16; off <<= 1) sum += __shfl_xor(sum, off);
        const float isum = 1.f / sum;
        #pragma unroll
        for (int nt = 0; nt < 4; ++nt)
          sP[r * 72 + nt * 16 + (l & 15)] = (bf16)(p[nt] * isum);
      }
  }

  // ---- PV ----
  f32x4 o[4][2] = {};
  #pragma unroll
  for (int ks = 0; ks < 2; ++ks) {
    const int k0 = ks * 32;
    bf16x8 pf[4];
    #pragma unroll
    for (int mt = 0; mt < 4; ++mt) pf[mt] = ld_frag(sP, mt * 16, k0, 72);
    #pragma unroll
    for (int nt = 0; nt < 2; ++nt) {
      const bf16x8 vf = ld_frag(sVT[wv], nt * 16, k0, 72);
      #pragma unroll
      for (int mt = 0; mt < 4; ++mt) o[mt][nt] = mfma16(pf[mt], vf, o[mt][nt]);
    }
  }
  __syncthreads();   // barrier 3: all sP reads done before attnout overwrites region
  {
    bf16* sAO = sU;  // [64][200]
    #pragma unroll
    for (int nt = 0; nt < 2; ++nt) {
      const int c = wv * 32 + nt * 16 + (l & 15);
      #pragma unroll
      for (int mt = 0; mt < 4; ++mt)
        #pragma unroll
        for (int i = 0; i < 4; ++i) {
          const int r = mt * 16 + (l >> 4) * 4 + i;
          sAO[r * 200 + c] = (bf16)o[mt][nt][i];
        }
    }
  }
  __syncthreads();   // barrier 4: attnout ready

  // ---- proj + residual, un-shift scatter ----
  {
    const bf16* sAO = sU;
    const bf16x8* bp = reinterpret_cast<const bf16x8*>(wpf) + l;
    f32x4 po[4][2] = {};
    #pragma unroll
    for (int ks = 0; ks < 6; ++ks) {
      const int k0 = ks * 32;
      bf16x8 af[4];
      #pragma unroll
      for (int mt = 0; mt < 4; ++mt) af[mt] = ld_frag(sAO, mt * 16, k0, 200);
      #pragma unroll
      for (int nt = 0; nt < 2; ++nt) {
        const bf16x8 bfr = bp[((wv * 2 + nt) * 6 + ks) * 64];
        #pragma unroll
        for (int mt = 0; mt < 4; ++mt) po[mt][nt] = mfma16(af[mt], bfr, po[mt][nt]);
      }
    }
    #pragma unroll
    for (int mt = 0; mt < 4; ++mt)
      #pragma unroll
      for (int i = 0; i < 4; ++i) {
        const int r = mt * 16 + (l >> 4) * 4 + i;
        if (r < 49) {
          const int th = r / 7, tw = r - 7 * th;
          const int ho = (wh * 7 + th + 3) % 56;
          const int wo = (ww * 7 + tw + 3) % 56;
          const size_t base = ((size_t)b * 3136 + ho * 56 + wo) * CD;
          #pragma unroll
          for (int nt = 0; nt < 2; ++nt) {
            const int c = wv * 32 + nt * 16 + (l & 15);
            out[base + c] = po[mt][nt][i] + projb[c] + x[base + c];
          }
        }
      }
  }
}

// ---------------- MLP v3: 64 tokens/block, 8 waves, K-streamed, packed-fragment weights ----
// LDS = 64*200*2 + 2*64*136*2 = 60.4 KB -> 2 blocks/CU (16 waves/CU).
// FC1 B-frags (12) prefetched into regs per chunk; all B-loads are 1KB coalesced.
__global__ __launch_bounds__(512, 4)
void swin_mlp_kernel(const float* __restrict__ n2w, const float* __restrict__ n2b,
                     const bf16* __restrict__ w1f, const float* __restrict__ fb1,
                     const bf16* __restrict__ w2f, const float* __restrict__ fb2,
                     float* __restrict__ io)
{
  __shared__ alignas(16) bf16 sA[64 * 200];       // LN2 output [64 tok][192 ch]
  __shared__ alignas(16) bf16 sH[2][64 * 136];    // hidden chunk dbuf [64 tok][128]
  const int l  = threadIdx.x & 63;
  const int wv = threadIdx.x >> 6;   // 0..7
  const int wr = wv & 1;             // M-half: rows wr*32..wr*32+31
  const int wc = wv >> 1;            // 0..3: N-quarter
  const size_t t0 = (size_t)blockIdx.x * 64;

  // ---- LN2 ----
  {
    const float w0 = n2w[l], w1 = n2w[l + 64], w2 = n2w[l + 128];
    const float c0 = n2b[l], c1 = n2b[l + 64], c2 = n2b[l + 128];
    for (int t = wv; t < 64; t += 8) {
      const float* xr = io + (t0 + t) * CD;
      float v0 = xr[l], v1 = xr[l + 64], v2 = xr[l + 128];
      float s  = v0 + v1 + v2;
      float ss = v0 * v0 + v1 * v1 + v2 * v2;
      #pragma unroll
      for (int off = 32; off; off >>= 1) { s += __shfl_xor(s, off); ss += __shfl_xor(ss, off); }
      const float mean = s * (1.f / 192.f);
      const float inv  = rsqrtf(ss * (1.f / 192.f) - mean * mean + 1e-5f);
      sA[t * 200 + l]       = (bf16)((v0 - mean) * inv * w0 + c0);
      sA[t * 200 + l + 64]  = (bf16)((v1 - mean) * inv * w1 + c1);
      sA[t * 200 + l + 128] = (bf16)((v2 - mean) * inv * w2 + c2);
    }
  }
  __syncthreads();

  f32x4 oacc[2][3] = {};   // FC2 out: rows wr*32+mt*16, cols wc*48+nt*16 (persistent)
  const bf16x8* w1p = reinterpret_cast<const bf16x8*>(w1f) + l;
  const bf16x8* w2p = reinterpret_cast<const bf16x8*>(w2f) + l;

  for (int kc = 0; kc < 6; ++kc) {
    bf16* hb = sH[kc & 1];
    // ---- FC1 chunk: h[64][kc*128 .. +128]; wave computes rows wr*32..+32, cols wc*32..+32
    {
      // prefetch the 12 B-fragments for this chunk (coalesced 1KB each)
      bf16x8 b1[2][6];
      const bf16x8* b1p = w1p + ((kc * 8 + wc * 2) * 6) * 64;
      #pragma unroll
      for (int nt = 0; nt < 2; ++nt)
        #pragma unroll
        for (int ks = 0; ks < 6; ++ks) b1[nt][ks] = b1p[(nt * 6 + ks) * 64];

      f32x4 acc[2][2] = {};
      #pragma unroll
      for (int ks = 0; ks < 6; ++ks) {
        const int k0 = ks * 32;
        bf16x8 af0 = ld_frag(sA, wr * 32,      k0, 200);
        bf16x8 af1 = ld_frag(sA, wr * 32 + 16, k0, 200);
        #pragma unroll
        for (int nt = 0; nt < 2; ++nt) {
          acc[0][nt] = mfma16(af0, b1[nt][ks], acc[0][nt]);
          acc[1][nt] = mfma16(af1, b1[nt][ks], acc[1][nt]);
        }
      }
      #pragma unroll
      for (int nt = 0; nt < 2; ++nt) {
        const int col = wc * 32 + nt * 16 + (l & 15);
        const float bias = fb1[kc * 128 + col];
        #pragma unroll
        for (int mt = 0; mt < 2; ++mt)
          #pragma unroll
          for (int i = 0; i < 4; ++i) {
            const int r = wr * 32 + mt * 16 + (l >> 4) * 4 + i;
            hb[r * 136 + col] = (bf16)gelu_f(acc[mt][nt][i] + bias);
          }
      }
    }
    __syncthreads();   // hb ready; dbuf makes this the ONLY barrier per chunk
    // ---- FC2 accumulate: out[64][192] += hb[64][128] x wt2-chunk
    {
      const bf16x8* b2p = w2p + (wc * 3 * 24 + kc * 4) * 64;
      #pragma unroll
      for (int ks = 0; ks < 4; ++ks) {
        bf16x8 af0 = ld_frag(hb, wr * 32,      ks * 32, 136);
        bf16x8 af1 = ld_frag(hb, wr * 32 + 16, ks * 32, 136);
        #pragma unroll
        for (int nt = 0; nt < 3; ++nt) {
          const bf16x8 bfr = b2p[(nt * 24 + ks) * 64];
          oacc[0][nt] = mfma16(af0, bfr, oacc[0][nt]);
          oacc[1][nt] = mfma16(af1, bfr, oacc[1][nt]);
        }
      }
    }
  }

  // ---- epilogue: bias + residual, in-place ----
  #pragma unroll
  for (int nt = 0; nt < 3; ++nt) {
    const int col = wc * 48 + nt * 16 + (l & 15);
    const float bias = fb2[col];
    #pragma unroll
    for (int mt = 0; mt < 2; ++mt)
      #pragma unroll
      for (int i = 0; i < 4; ++i) {
        const int r = wr * 32 + mt * 16 + (l >> 4) * 4 + i;
        const size_t idx = (t0 + r) * CD + col;
        io[idx] = oacc[mt][nt][i] + bias + io[idx];
      }
  }
}

extern "C" void kernel_launch(void* const* d_in, const int* in_sizes, int n_in,
                              void* d_out, int out_size, void* d_ws, size_t ws_size,
                              hipStream_t stream) {
  const float* x     = (const float*)d_in[0];
  const float* n1w   = (const float*)d_in[1];
  const float* n1b   = (const float*)d_in[2];
  const float* qkvw  = (const float*)d_in[3];
  const float* qkvb  = (const float*)d_in[4];
  const float* projw = (const float*)d_in[5];
  const float* projb = (const float*)d_in[6];
  const float* relb  = (const float*)d_in[7];
  const float* n2w   = (const float*)d_in[8];
  const float* n2b   = (const float*)d_in[9];
  const float* f1w   = (const float*)d_in[10];
  const float* f1b   = (const float*)d_in[11];
  const float* f2w   = (const float*)d_in[12];
  const float* f2b   = (const float*)d_in[13];

  char* ws = (char*)d_ws;
  bf16* wqf = (bf16*)(ws + 0);        // qkv packed: 36*6*64*16B  = 221184
  bf16* wpf = (bf16*)(ws + 221184);   // proj packed: 12*6*64*16B =  73728
  bf16* w1f = (bf16*)(ws + 294912);   // fc1 packed: 48*6*64*16B  = 294912
  bf16* w2f = (bf16*)(ws + 589824);   // fc2 packed: 12*24*64*16B = 294912

  prep_pack<<<(36 * 6 * 64 + 255) / 256, 256, 0, stream>>>(qkvw, wqf, 192, 576);
  prep_pack<<<(12 * 6 * 64 + 255) / 256, 256, 0, stream>>>(projw, wpf, 192, 192);
  prep_pack<<<(48 * 6 * 64 + 255) / 256, 256, 0, stream>>>(f1w, w1f, 192, 768);
  prep_pack<<<(12 * 24 * 64 + 255) / 256, 256, 0, stream>>>(f2w, w2f, 768, 192);

  swin_attn_kernel<<<4096, 384, 0, stream>>>(x, n1w, n1b, wqf, qkvb, wpf, projb, relb, (float*)d_out);
  swin_mlp_kernel<<<3136, 512, 0, stream>>>(n2w, n2b, w1f, f1b, w2f, f2b, (float*)d_out);
}

// Round 4
// 668.335 us; speedup vs baseline: 1.4612x; 1.0127x over previous
//
#include <hip/hip_runtime.h>
#include <hip/hip_bf16.h>
#include <math.h>

typedef __bf16 bf16;
typedef bf16  bf16x8 __attribute__((ext_vector_type(8)));
typedef float f32x4  __attribute__((ext_vector_type(4)));

#define CD 192
#define NHEADS 6

// One fragment convention for BOTH A and B operands of mfma_f32_16x16x32_bf16:
// lane l supplies (row/col) = r0 + (l&15), k = k0 + 8*(l>>4) + j  (8 contiguous bf16 = 16B).
__device__ __forceinline__ bf16x8 ld_frag(const bf16* p, int r0, int k0, int ld) {
  const int l = threadIdx.x & 63;
  return *reinterpret_cast<const bf16x8*>(p + (r0 + (l & 15)) * ld + (k0 + 8 * (l >> 4)));
}

__device__ __forceinline__ f32x4 mfma16(bf16x8 a, bf16x8 b, f32x4 c) {
  return __builtin_amdgcn_mfma_f32_16x16x32_bf16(a, b, c, 0, 0, 0);
}

// tanh-approx GELU: max abs err ~1e-3.
__device__ __forceinline__ float gelu_f(float v) {
  return v / (1.f + __expf(-1.5957691216057308f * (v + 0.044715f * v * v * v)));
}

// ---------------- weight pack: fragment-major layout --------------------------------------
// src is [K][N] row-major. For n-tile ng (16 wide), k-tile kt (32 deep), lane l's bf16x8
// fragment (n = ng*16+(l&15), k = kt*32+8*(l>>4)+j) stored at dst[((ng*(K/32)+kt)*64+l)*8].
__global__ void prep_pack(const float* __restrict__ src, bf16* __restrict__ dst, int K, int N) {
  const int t = blockIdx.x * 256 + threadIdx.x;
  const int ktiles = K >> 5;
  const int total = (N >> 4) * ktiles * 64;
  if (t >= total) return;
  const int l  = t & 63;
  const int r  = t >> 6;
  const int kt = r % ktiles;
  const int ng = r / ktiles;
  const int n  = ng * 16 + (l & 15);
  const int k0 = kt * 32 + 8 * (l >> 4);
  bf16x8 v;
  #pragma unroll
  for (int j = 0; j < 8; ++j) v[j] = (bf16)src[(size_t)(k0 + j) * N + n];
  *(reinterpret_cast<bf16x8*>(dst) + t) = v;
}

// ---------------- attention: 1 block = 1 window; 12 waves = (head, row-half) ---------------
__global__ __launch_bounds__(768, 1)
void swin_attn_kernel(const float* __restrict__ x,
                      const float* __restrict__ n1w, const float* __restrict__ n1b,
                      const bf16* __restrict__ wqf, const float* __restrict__ qkvb,
                      const bf16* __restrict__ wpf, const float* __restrict__ projb,
                      const float* __restrict__ relb,
                      float* __restrict__ out)
{
  __shared__ alignas(16) bf16 sQ[NHEADS][64 * 40];   // [head][row][chan 0..31] pad 40
  __shared__ alignas(16) bf16 sK[NHEADS][64 * 40];
  __shared__ alignas(16) bf16 sVT[NHEADS][32 * 72];  // [head][chan][key] pad 72
  // union: phase<=1: sA [64][200]; phase 2-3: sP[head][64][72]; phase 4: attnout [64][200]
  __shared__ alignas(16) bf16 sU[NHEADS * 64 * 72];

  const int l    = threadIdx.x & 63;
  const int wv   = threadIdx.x >> 6;     // 0..11
  const int h    = wv >> 1;              // head
  const int half = wv & 1;               // row-half: rows half*32 .. +32
  const int r0w  = half * 32;
  const int b  = blockIdx.x >> 6;
  const int wi = blockIdx.x & 63;
  const int wh = wi >> 3, ww = wi & 7;

  bf16* sA = sU;   // [64][200]

  // ---- LN1 with shifted-window gather ----
  {
    const float w0 = n1w[l], w1 = n1w[l + 64], w2 = n1w[l + 128];
    const float c0 = n1b[l], c1 = n1b[l + 64], c2 = n1b[l + 128];
    for (int t = wv; t < 49; t += 12) {
      const int th = t / 7, tw = t - 7 * th;
      const int ho = (wh * 7 + th + 3) % 56;     // roll(-3) folded into gather
      const int wo = (ww * 7 + tw + 3) % 56;
      const float* xr = x + ((size_t)b * 3136 + ho * 56 + wo) * CD;
      float v0 = xr[l], v1 = xr[l + 64], v2 = xr[l + 128];
      float s  = v0 + v1 + v2;
      float ss = v0 * v0 + v1 * v1 + v2 * v2;
      #pragma unroll
      for (int off = 32; off; off >>= 1) { s += __shfl_xor(s, off); ss += __shfl_xor(ss, off); }
      const float mean = s * (1.f / 192.f);
      const float inv  = rsqrtf(ss * (1.f / 192.f) - mean * mean + 1e-5f);
      sA[t * 200 + l]       = (bf16)((v0 - mean) * inv * w0 + c0);
      sA[t * 200 + l + 64]  = (bf16)((v1 - mean) * inv * w1 + c1);
      sA[t * 200 + l + 128] = (bf16)((v2 - mean) * inv * w2 + c2);
    }
    for (int i = threadIdx.x; i < 15 * 200; i += 768) sA[49 * 200 + i] = (bf16)0.f;
  }
  __syncthreads();   // barrier 1: sA ready

  // ---- QKV GEMM: wave computes rows [r0w, r0w+32) of head h's 96 cols (q,k,v x 32) ----
  {
    const bf16x8* bq = reinterpret_cast<const bf16x8*>(wqf) + l;
    f32x4 acc[6][2] = {};
    #pragma unroll
    for (int ks = 0; ks < 6; ++ks) {
      const int k0 = ks * 32;
      bf16x8 af0 = ld_frag(sA, r0w,      k0, 200);
      bf16x8 af1 = ld_frag(sA, r0w + 16, k0, 200);
      #pragma unroll
      for (int nt = 0; nt < 6; ++nt) {
        const int ng = (nt >> 1) * 12 + h * 2 + (nt & 1);    // col-tile of [576]
        const bf16x8 bfr = bq[(ng * 6 + ks) * 64];
        acc[nt][0] = mfma16(af0, bfr, acc[nt][0]);
        acc[nt][1] = mfma16(af1, bfr, acc[nt][1]);
      }
    }
    #pragma unroll
    for (int nt = 0; nt < 6; ++nt) {
      const int which = nt >> 1;
      const int c = (nt & 1) * 16 + (l & 15);             // channel within head
      const float bias = qkvb[which * 192 + h * 32 + c];
      #pragma unroll
      for (int mt = 0; mt < 2; ++mt)
        #pragma unroll
        for (int i = 0; i < 4; ++i) {
          const int r = r0w + mt * 16 + (l >> 4) * 4 + i;
          const float v = acc[nt][mt][i] + bias;
          if (which == 0)      sQ[h][r * 40 + c] = (bf16)(v * 0.17677669529663689f); // pre-scale q
          else if (which == 1) sK[h][r * 40 + c] = (bf16)v;
          else                 sVT[h][c * 72 + r] = (bf16)v;  // V transposed for PV B-frags
        }
    }
  }
  __syncthreads();   // barrier 2: sA dead -> sP region may be written

  // ---- scores + bias + mask + softmax ----
  bf16* sP = sU + h * (64 * 72);
  {
    f32x4 sc[2][4] = {};
    bf16x8 qf0 = ld_frag(sQ[h], r0w,      0, 40);
    bf16x8 qf1 = ld_frag(sQ[h], r0w + 16, 0, 40);
    #pragma unroll
    for (int nt = 0; nt < 4; ++nt) {
      const bf16x8 kf = ld_frag(sK[h], nt * 16, 0, 40);
      sc[0][nt] = mfma16(qf0, kf, sc[0][nt]);
      sc[1][nt] = mfma16(qf1, kf, sc[1][nt]);
    }
    int kkv[4], khv[4], kwv[4], clk[4];
    #pragma unroll
    for (int nt = 0; nt < 4; ++nt) {
      kkv[nt] = nt * 16 + (l & 15);
      khv[nt] = kkv[nt] / 7; kwv[nt] = kkv[nt] - 7 * khv[nt];
      const int gh = wh * 7 + khv[nt], gw = ww * 7 + kwv[nt];
      clk[nt] = (gh < 49 ? 0 : (gh < 53 ? 1 : 2)) * 3 + (gw < 49 ? 0 : (gw < 53 ? 1 : 2));
    }
    #pragma unroll
    for (int mt = 0; mt < 2; ++mt)
      #pragma unroll
      for (int i = 0; i < 4; ++i) {
        const int r = r0w + mt * 16 + (l >> 4) * 4 + i;    // query token
        const int rh = r / 7, rw = r - 7 * rh;
        const int gh = wh * 7 + rh, gw = ww * 7 + rw;
        const int clr = (gh < 49 ? 0 : (gh < 53 ? 1 : 2)) * 3 + (gw < 49 ? 0 : (gw < 53 ? 1 : 2));
        float v[4];
        #pragma unroll
        for (int nt = 0; nt < 4; ++nt) {
          if (r < 49 && kkv[nt] < 49) {
            const int bidx = (rh - khv[nt] + 6) * 13 + (rw - kwv[nt] + 6);
            v[nt] = sc[mt][nt][i] + relb[bidx * 6 + h] + ((clr != clk[nt]) ? -100.f : 0.f);
          } else v[nt] = -1e30f;
        }
        float mx = fmaxf(fmaxf(v[0], v[1]), fmaxf(v[2], v[3]));
        #pragma unroll
        for (int off = 1; off < 16; off <<= 1) mx = fmaxf(mx, __shfl_xor(mx, off));
        float p[4], sum = 0.f;
        #pragma unroll
        for (int nt = 0; nt < 4; ++nt) { p[nt] = __expf(v[nt] - mx); sum += p[nt]; }
        #pragma unroll
        for (int off = 1; off < 16; off <<= 1) sum += __shfl_xor(sum, off);
        const float isum = 1.f / sum;
        #pragma unroll
        for (int nt = 0; nt < 4; ++nt)
          sP[r * 72 + nt * 16 + (l & 15)] = (bf16)(p[nt] * isum);
      }
  }

  // ---- PV: rows [r0w, +32), output channels of head h ----
  f32x4 o[2][2] = {};
  #pragma unroll
  for (int ks = 0; ks < 2; ++ks) {
    const int k0 = ks * 32;
    bf16x8 pf0 = ld_frag(sP, r0w,      k0, 72);
    bf16x8 pf1 = ld_frag(sP, r0w + 16, k0, 72);
    #pragma unroll
    for (int nt = 0; nt < 2; ++nt) {
      const bf16x8 vf = ld_frag(sVT[h], nt * 16, k0, 72);
      o[0][nt] = mfma16(pf0, vf, o[0][nt]);
      o[1][nt] = mfma16(pf1, vf, o[1][nt]);
    }
  }
  __syncthreads();   // barrier 3: all sP reads done before attnout overwrites region
  {
    bf16* sAO = sU;  // [64][200]
    #pragma unroll
    for (int nt = 0; nt < 2; ++nt) {
      const int c = h * 32 + nt * 16 + (l & 15);
      #pragma unroll
      for (int mt = 0; mt < 2; ++mt)
        #pragma unroll
        for (int i = 0; i < 4; ++i) {
          const int r = r0w + mt * 16 + (l >> 4) * 4 + i;
          sAO[r * 200 + c] = (bf16)o[mt][nt][i];
        }
    }
  }
  __syncthreads();   // barrier 4: attnout ready

  // ---- proj + residual, un-shift scatter: wave does rows [r0w,+32) x cols [h*32,+32) ----
  {
    const bf16* sAO = sU;
    const bf16x8* bp = reinterpret_cast<const bf16x8*>(wpf) + l;
    f32x4 po[2][2] = {};
    #pragma unroll
    for (int ks = 0; ks < 6; ++ks) {
      const int k0 = ks * 32;
      bf16x8 af0 = ld_frag(sAO, r0w,      k0, 200);
      bf16x8 af1 = ld_frag(sAO, r0w + 16, k0, 200);
      #pragma unroll
      for (int nt = 0; nt < 2; ++nt) {
        const bf16x8 bfr = bp[((h * 2 + nt) * 6 + ks) * 64];
        po[0][nt] = mfma16(af0, bfr, po[0][nt]);
        po[1][nt] = mfma16(af1, bfr, po[1][nt]);
      }
    }
    #pragma unroll
    for (int mt = 0; mt < 2; ++mt)
      #pragma unroll
      for (int i = 0; i < 4; ++i) {
        const int r = r0w + mt * 16 + (l >> 4) * 4 + i;
        if (r < 49) {
          const int th = r / 7, tw = r - 7 * th;
          const int ho = (wh * 7 + th + 3) % 56;
          const int wo = (ww * 7 + tw + 3) % 56;
          const size_t base = ((size_t)b * 3136 + ho * 56 + wo) * CD;
          #pragma unroll
          for (int nt = 0; nt < 2; ++nt) {
            const int c = h * 32 + nt * 16 + (l & 15);
            out[base + c] = po[mt][nt][i] + projb[c] + x[base + c];
          }
        }
      }
  }
}

// ---------------- MLP v3: 64 tokens/block, 8 waves, K-streamed, packed-fragment weights ----
__global__ __launch_bounds__(512, 4)
void swin_mlp_kernel(const float* __restrict__ n2w, const float* __restrict__ n2b,
                     const bf16* __restrict__ w1f, const float* __restrict__ fb1,
                     const bf16* __restrict__ w2f, const float* __restrict__ fb2,
                     float* __restrict__ io)
{
  __shared__ alignas(16) bf16 sA[64 * 200];       // LN2 output [64 tok][192 ch]
  __shared__ alignas(16) bf16 sH[2][64 * 136];    // hidden chunk dbuf [64 tok][128]
  const int l  = threadIdx.x & 63;
  const int wv = threadIdx.x >> 6;   // 0..7
  const int wr = wv & 1;             // M-half
  const int wc = wv >> 1;            // N-quarter
  const size_t t0 = (size_t)blockIdx.x * 64;

  // ---- LN2 ----
  {
    const float w0 = n2w[l], w1 = n2w[l + 64], w2 = n2w[l + 128];
    const float c0 = n2b[l], c1 = n2b[l + 64], c2 = n2b[l + 128];
    for (int t = wv; t < 64; t += 8) {
      const float* xr = io + (t0 + t) * CD;
      float v0 = xr[l], v1 = xr[l + 64], v2 = xr[l + 128];
      float s  = v0 + v1 + v2;
      float ss = v0 * v0 + v1 * v1 + v2 * v2;
      #pragma unroll
      for (int off = 32; off; off >>= 1) { s += __shfl_xor(s, off); ss += __shfl_xor(ss, off); }
      const float mean = s * (1.f / 192.f);
      const float inv  = rsqrtf(ss * (1.f / 192.f) - mean * mean + 1e-5f);
      sA[t * 200 + l]       = (bf16)((v0 - mean) * inv * w0 + c0);
      sA[t * 200 + l + 64]  = (bf16)((v1 - mean) * inv * w1 + c1);
      sA[t * 200 + l + 128] = (bf16)((v2 - mean) * inv * w2 + c2);
    }
  }
  __syncthreads();

  f32x4 oacc[2][3] = {};   // FC2 out (persistent)
  const bf16x8* w1p = reinterpret_cast<const bf16x8*>(w1f) + l;
  const bf16x8* w2p = reinterpret_cast<const bf16x8*>(w2f) + l;

  for (int kc = 0; kc < 6; ++kc) {
    bf16* hb = sH[kc & 1];
    {
      bf16x8 b1[2][6];
      const bf16x8* b1p = w1p + ((kc * 8 + wc * 2) * 6) * 64;
      #pragma unroll
      for (int nt = 0; nt < 2; ++nt)
        #pragma unroll
        for (int ks = 0; ks < 6; ++ks) b1[nt][ks] = b1p[(nt * 6 + ks) * 64];

      f32x4 acc[2][2] = {};
      #pragma unroll
      for (int ks = 0; ks < 6; ++ks) {
        const int k0 = ks * 32;
        bf16x8 af0 = ld_frag(sA, wr * 32,      k0, 200);
        bf16x8 af1 = ld_frag(sA, wr * 32 + 16, k0, 200);
        #pragma unroll
        for (int nt = 0; nt < 2; ++nt) {
          acc[0][nt] = mfma16(af0, b1[nt][ks], acc[0][nt]);
          acc[1][nt] = mfma16(af1, b1[nt][ks], acc[1][nt]);
        }
      }
      #pragma unroll
      for (int nt = 0; nt < 2; ++nt) {
        const int col = wc * 32 + nt * 16 + (l & 15);
        const float bias = fb1[kc * 128 + col];
        #pragma unroll
        for (int mt = 0; mt < 2; ++mt)
          #pragma unroll
          for (int i = 0; i < 4; ++i) {
            const int r = wr * 32 + mt * 16 + (l >> 4) * 4 + i;
            hb[r * 136 + col] = (bf16)gelu_f(acc[mt][nt][i] + bias);
          }
      }
    }
    __syncthreads();
    {
      const bf16x8* b2p = w2p + (wc * 3 * 24 + kc * 4) * 64;
      #pragma unroll
      for (int ks = 0; ks < 4; ++ks) {
        bf16x8 af0 = ld_frag(hb, wr * 32,      ks * 32, 136);
        bf16x8 af1 = ld_frag(hb, wr * 32 + 16, ks * 32, 136);
        #pragma unroll
        for (int nt = 0; nt < 3; ++nt) {
          const bf16x8 bfr = b2p[(nt * 24 + ks) * 64];
          oacc[0][nt] = mfma16(af0, bfr, oacc[0][nt]);
          oacc[1][nt] = mfma16(af1, bfr, oacc[1][nt]);
        }
      }
    }
  }

  #pragma unroll
  for (int nt = 0; nt < 3; ++nt) {
    const int col = wc * 48 + nt * 16 + (l & 15);
    const float bias = fb2[col];
    #pragma unroll
    for (int mt = 0; mt < 2; ++mt)
      #pragma unroll
      for (int i = 0; i < 4; ++i) {
        const int r = wr * 32 + mt * 16 + (l >> 4) * 4 + i;
        const size_t idx = (t0 + r) * CD + col;
        io[idx] = oacc[mt][nt][i] + bias + io[idx];
      }
  }
}

extern "C" void kernel_launch(void* const* d_in, const int* in_sizes, int n_in,
                              void* d_out, int out_size, void* d_ws, size_t ws_size,
                              hipStream_t stream) {
  const float* x     = (const float*)d_in[0];
  const float* n1w   = (const float*)d_in[1];
  const float* n1b   = (const float*)d_in[2];
  const float* qkvw  = (const float*)d_in[3];
  const float* qkvb  = (const float*)d_in[4];
  const float* projw = (const float*)d_in[5];
  const float* projb = (const float*)d_in[6];
  const float* relb  = (const float*)d_in[7];
  const float* n2w   = (const float*)d_in[8];
  const float* n2b   = (const float*)d_in[9];
  const float* f1w   = (const float*)d_in[10];
  const float* f1b   = (const float*)d_in[11];
  const float* f2w   = (const float*)d_in[12];
  const float* f2b   = (const float*)d_in[13];

  char* ws = (char*)d_ws;
  bf16* wqf = (bf16*)(ws + 0);        // qkv packed: 36*6*64*16B  = 221184
  bf16* wpf = (bf16*)(ws + 221184);   // proj packed: 12*6*64*16B =  73728
  bf16* w1f = (bf16*)(ws + 294912);   // fc1 packed: 48*6*64*16B  = 294912
  bf16* w2f = (bf16*)(ws + 589824);   // fc2 packed: 12*24*64*16B = 294912

  prep_pack<<<(36 * 6 * 64 + 255) / 256, 256, 0, stream>>>(qkvw, wqf, 192, 576);
  prep_pack<<<(12 * 6 * 64 + 255) / 256, 256, 0, stream>>>(projw, wpf, 192, 192);
  prep_pack<<<(48 * 6 * 64 + 255) / 256, 256, 0, stream>>>(f1w, w1f, 192, 768);
  prep_pack<<<(12 * 24 * 64 + 255) / 256, 256, 0, stream>>>(f2w, w2f, 768, 192);

  swin_attn_kernel<<<4096, 768, 0, stream>>>(x, n1w, n1b, wqf, qkvb, wpf, projb, relb, (float*)d_out);
  swin_mlp_kernel<<<3136, 512, 0, stream>>>(n2w, n2b, w1f, f1b, w2f, f2b, (float*)d_out);
}